// Round 6
// baseline (573.452 us; speedup 1.0000x reference)
//
#include <hip/hip_runtime.h>
#include <stdint.h>

#define NN 100000
#define NE 3200000
#define FIN 503
#define COUT 32
#define NSLOPE 0.2f

#define BSH 6                    // 64 dst nodes per bucket
#define NB 1563                  // ceil(NN / 64)
#define NGB 1563                 // gemm blocks: ceil(NN/64)
#define NHB 512                  // hist segments / scatter blocks
#define EPB (NE / NHB)           // 6250 edges per segment (exact)
#define NSB 7                    // scan blocks: ceil(NB/256)
#define MAXBE 2560               // max edges per bucket (lambda=2048, +11 sigma)

typedef __bf16 bf16x8 __attribute__((ext_vector_type(8)));
typedef float  f32x4  __attribute__((ext_vector_type(4)));

__device__ __forceinline__ unsigned short bf1(float f) {
    unsigned u = __float_as_uint(f);
    u = (u + 0x7FFFu + ((u >> 16) & 1u)) >> 16;   // RNE to bf16
    return (unsigned short)u;
}
__device__ __forceinline__ float unbf(unsigned short h) {
    return __uint_as_float(((unsigned)h) << 16);
}

// ---------------- k_fused1: gemm blocks [0,NGB) + hist blocks [NGB,NGB+NHB) ---
// Heterogeneous dispatch: BW/MFMA-bound gemm co-resident with latency-bound
// histogram -> mutual latency hiding. gemm reads W directly (L2-hot 64 KB),
// killing the wprep dependency that forced serialization.
#define GR 64

__global__ __launch_bounds__(256)
void k_fused1(const float* __restrict__ x, const float* __restrict__ W,
              const float* __restrict__ att_s, const float* __restrict__ att_d,
              unsigned short* __restrict__ xlb,
              float* __restrict__ a_src, float* __restrict__ a_dst,
              const int* __restrict__ ei_dst, const float* __restrict__ ew,
              float* __restrict__ partial, unsigned* __restrict__ part,
              unsigned* __restrict__ done)
{
    __shared__ __align__(16) float xs[2][GR][36];          // 18.4 KB (union)
    const int t = threadIdx.x;

    if (blockIdx.x >= NGB) {
        // ---------------- hist path ----------------
        unsigned* h = (unsigned*)&xs[0][0][0];             // NB counters (6.3 KB)
        __shared__ float wsum[4];
        const int hb = blockIdx.x - NGB;
        for (int i = t; i < NB; i += 256) h[i] = 0u;
        __syncthreads();
        const int base = hb * EPB;
        for (int i = t; i < EPB; i += 256)
            atomicAdd(&h[ei_dst[base + i] >> BSH], 1u);
        // ew partial sum (float4 grid-stride)
        const float4* ew4 = (const float4*)ew;
        float s = 0.f;
        for (int i = hb * 256 + t; i < NE / 4; i += NHB * 256) {
            float4 v = ew4[i];
            s += v.x + v.y + v.z + v.w;
        }
        #pragma unroll
        for (int off = 32; off > 0; off >>= 1) s += __shfl_xor(s, off);
        if ((t & 63) == 0) wsum[t >> 6] = s;
        __syncthreads();
        if (t == 0) partial[hb] = wsum[0] + wsum[1] + wsum[2] + wsum[3];
        for (int i = t; i < NB; i += 256)
            part[(size_t)hb * NB + i] = h[i];
        return;
    }

    // ---------------- gemm path ----------------
    if (blockIdx.x == 0 && t == 0) *done = 0u;             // for k_scan ticket
    unsigned short* os = (unsigned short*)&xs[0][0][0];    // epilogue union (5 KB)
    const int wv = t >> 6, lane = t & 63;
    const int m16 = lane & 15, quad = lane >> 4;
    const int row0 = blockIdx.x * GR;
    const int srow = t >> 5;            // staging: 8 rows per pass
    const int scol = t & 31;            // staging: dword within chunk
    const int rowf = wv * 16 + m16;     // fragment row within block
    const float* wr0 = W + (size_t)m16 * FIN;        // B-frag rows (L2-hot)
    const float* wr1 = W + (size_t)(m16 + 16) * FIN;

    auto stage = [&](int ch, int buf) {
        const int k = ch * 32 + scol;
        const bool ok = (k < FIN);
        #pragma unroll
        for (int p = 0; p < 8; ++p) {
            int r = p * 8 + srow;
            int rg = row0 + r;
            rg = (rg < NN) ? rg : (NN - 1);
            xs[buf][r][scol] = ok ? x[(size_t)rg * FIN + k] : 0.f;
        }
    };

    f32x4 acc0 = {0.f, 0.f, 0.f, 0.f};
    f32x4 acc1 = {0.f, 0.f, 0.f, 0.f};

    stage(0, 0);
    for (int ch = 0; ch < 16; ++ch) {
        __syncthreads();                          // stage(ch) ready; buf (ch+1)&1 free
        if (ch < 15) stage(ch + 1, (ch + 1) & 1); // prefetch next chunk
        const int kb = ch * 32 + quad * 8;
        float av[8];
        *(f32x4*)&av[0] = *(const f32x4*)&xs[ch & 1][rowf][quad * 8];
        *(f32x4*)&av[4] = *(const f32x4*)&xs[ch & 1][rowf][quad * 8 + 4];
        bf16x8 af, b0f, b1f;
        if (ch < 15) {
            #pragma unroll
            for (int j = 0; j < 8; ++j) {
                af[j]  = (__bf16)av[j];
                b0f[j] = (__bf16)wr0[kb + j];
                b1f[j] = (__bf16)wr1[kb + j];
            }
        } else {
            #pragma unroll
            for (int j = 0; j < 8; ++j) {
                af[j]  = (__bf16)av[j];
                bool ok = (kb + j < FIN);
                b0f[j] = (__bf16)(ok ? wr0[kb + j] : 0.f);
                b1f[j] = (__bf16)(ok ? wr1[kb + j] : 0.f);
            }
        }
        acc0 = __builtin_amdgcn_mfma_f32_16x16x32_bf16(af, b0f, acc0, 0, 0, 0);
        acc1 = __builtin_amdgcn_mfma_f32_16x16x32_bf16(af, b1f, acc1, 0, 0, 0);
    }
    // last compute read xs[1]; os overlays xs[0] -> no address overlap race

    // epilogue: C-layout (row=quad*4+r, col=m16) -> row-major bf16 via LDS
    #pragma unroll
    for (int r = 0; r < 4; ++r) {
        int rr = wv * 16 + quad * 4 + r;
        os[rr * 40 + m16]      = bf1(acc0[r]);
        os[rr * 40 + 16 + m16] = bf1(acc1[r]);
    }
    __syncthreads();
    {
        int r = t >> 2, c0 = (t & 3) * 8;
        int grow = row0 + r;
        uint4 o = *(const uint4*)&os[r * 40 + c0];
        // attention logits (k_attn folded): partial dot over 8 channels,
        // reduce across the 4 threads of this row (width-4 shuffle)
        float s = 0.f, dd = 0.f;
        const unsigned short* oh = (const unsigned short*)&o;
        #pragma unroll
        for (int j = 0; j < 8; ++j) {
            float v = unbf(oh[j]);
            s  += v * att_s[c0 + j];
            dd += v * att_d[c0 + j];
        }
        s  += __shfl_xor(s, 1, 4);  s  += __shfl_xor(s, 2, 4);
        dd += __shfl_xor(dd, 1, 4); dd += __shfl_xor(dd, 2, 4);
        if (grow < NN) {
            *(uint4*)&xlb[(size_t)grow * COUT + c0] = o;
            if ((t & 3) == 0) { a_src[grow] = s; a_dst[grow] = dd; }
        }
    }
}

// ---------------- k_scan: one bucket per THREAD, coalesced row-major walk -----
// part is [seg][bkt]; wave-adjacent threads own adjacent buckets -> coalesced.
// unroll 8 keeps the dependent chain at 64 steps despite 512 segments.
__global__ __launch_bounds__(256)
void k_scan(unsigned* __restrict__ part, unsigned* __restrict__ colsum,
            unsigned* __restrict__ done, const float* __restrict__ partial,
            const float* __restrict__ W_edge, const float* __restrict__ att_e,
            float* __restrict__ stats, unsigned* __restrict__ bbase)
{
    const int t = threadIdx.x;
    const int bkt = blockIdx.x * 256 + t;
    if (bkt < NB) {
        unsigned run = 0u;
        #pragma unroll 1
        for (int s = 0; s < NHB; s += 8) {
            unsigned v[8];
            #pragma unroll
            for (int j = 0; j < 8; ++j) v[j] = part[(size_t)(s + j) * NB + bkt];
            #pragma unroll
            for (int j = 0; j < 8; ++j) {
                part[(size_t)(s + j) * NB + bkt] = run;
                run += v[j];
            }
        }
        colsum[bkt] = run;
    }
    __threadfence();
    __syncthreads();
    __shared__ unsigned winner;
    if (t == 0) winner = atomicAdd(done, 1u);
    __syncthreads();
    if (winner != NSB - 1) return;

    // ---- last block: stats finalize ----
    __shared__ float fs[256];
    fs[t] = partial[t] + partial[t + 256];
    __syncthreads();
    for (int off = 128; off > 0; off >>= 1) {
        if (t < off) fs[t] += fs[t + off];
        __syncthreads();
    }
    if (t == 0) {
        stats[0] = fs[0];
        float k = 0.f;
        for (int c = 0; c < COUT; ++c) k += W_edge[c] * att_e[c];
        stats[1] = k;
    }
    __syncthreads();
    // ---- bucket-base exclusive scan (atomic loads: device-scope coherent) ----
    __shared__ unsigned sm[256];
    __shared__ unsigned carry;
    if (t == 0) carry = 0u;
    __syncthreads();
    for (int c0 = 0; c0 < NB; c0 += 256) {
        int i = c0 + t;
        unsigned cv = (i < NB) ? atomicAdd(&colsum[i], 0u) : 0u;
        sm[t] = cv;
        for (int off = 1; off < 256; off <<= 1) {
            __syncthreads();
            unsigned tv = (t >= off) ? sm[t - off] : 0u;
            __syncthreads();
            sm[t] += tv;
        }
        __syncthreads();
        if (i < NB) bbase[i] = carry + sm[t] - cv;
        __syncthreads();
        if (t == 0) carry += sm[255];
        __syncthreads();
    }
    if (t == 0) bbase[NB] = carry;                // == NE
}

// ---------------- scatter edges into bucket-grouped order (LDS cursors) -------
__global__ __launch_bounds__(256)
void k_scatter(const int* __restrict__ ei, const float* __restrict__ ew,
               const float* __restrict__ a_src, const float* __restrict__ stats,
               const unsigned* __restrict__ part, const unsigned* __restrict__ bbase,
               uint2* __restrict__ csr)
{
    __shared__ unsigned cur[NB];
    const int b = blockIdx.x;
    const int t = threadIdx.x;
    for (int i = t; i < NB; i += 256)
        cur[i] = bbase[i] + part[(size_t)b * NB + i];
    __syncthreads();
    const float kc = stats[1];
    const int base = b * EPB;
    for (int i = t; i < EPB; i += 256) {
        int e = base + i;
        int s = ei[e];
        int d = ei[NE + e];
        float pre = a_src[s] + kc * ew[e];
        unsigned pos = atomicAdd(&cur[d >> BSH], 1u);
        csr[pos] = make_uint2((unsigned)s | ((unsigned)(d & 63) << 20),
                              __float_as_uint(pre));
    }
}

// ---------------- per-bucket softmax aggregation --------------------------------
// Two-pass in-place LDS counting sort (pass 2 is L1-hot). 21 KB LDS, 44 VGPR ->
// 7 blocks/CU -> whole 1563-block grid resident in one scheduling round.
__global__ __launch_bounds__(256)
void k_aggr(const uint2* __restrict__ csr, const unsigned* __restrict__ bbase,
            const float* __restrict__ a_src, const float* __restrict__ a_dst,
            const unsigned short* __restrict__ xlb, const float* __restrict__ stats,
            const float* __restrict__ bias_conv, const float* __restrict__ Wb,
            const float* __restrict__ bb, const float* __restrict__ Ww,
            const float* __restrict__ mask, float* __restrict__ out_b,
            float* __restrict__ hw)
{
    __shared__ uint2 rec[MAXBE];
    __shared__ unsigned seg[65], cur[64];
    const int t = threadIdx.x;
    const int b = blockIdx.x;
    const int jb = (int)bbase[b];
    int ne = (int)bbase[b + 1] - jb;
    if (ne > MAXBE) ne = MAXBE;                   // statistically unreachable

    if (t < 64) cur[t] = 0u;
    __syncthreads();
    // pass 1: histogram of dst-locals
    for (int i = t; i < ne; i += 256)
        atomicAdd(&cur[csr[jb + i].x >> 20], 1u);
    __syncthreads();
    // exclusive scan of 64 counters in wave 0 (shfl-based)
    if (t < 64) {
        unsigned v = cur[t];
        unsigned s = v;
        #pragma unroll
        for (int off = 1; off < 64; off <<= 1) {
            unsigned u = __shfl_up(s, off, 64);
            if (t >= off) s += u;
        }
        seg[t + 1] = s;           // inclusive
        cur[t] = s - v;           // exclusive -> running cursor
        if (t == 0) seg[0] = 0u;
    }
    __syncthreads();
    // pass 2: scatter into sorted position (csr segment L1-hot from pass 1)
    for (int i = t; i < ne; i += 256) {
        uint2 r = csr[jb + i];
        unsigned pos = atomicAdd(&cur[r.x >> 20], 1u);
        rec[pos] = r;
    }
    __syncthreads();

    const float kmean = stats[1] * (stats[0] * (1.f / NE));   // kc * mean(ew)
    const int lane = t & 31;
    for (int dl = t >> 5; dl < 64; dl += 8) {
        int d = (b << BSH) + dl;
        if (d >= NN) continue;                    // warp-uniform
        const float adv = a_dst[d];
        // self loop (edge_attr = mean), computed inline
        float a0 = a_src[d] + adv + kmean;
        a0 = (a0 > 0.f) ? a0 : NSLOPE * a0;
        const float ps = __expf(a0);
        float l = 0.f;
        float acc = ps * unbf(xlb[(size_t)d * COUT + lane]);
        const int j0 = (int)seg[dl], j1 = (int)seg[dl + 1];
        for (int tb = j0; tb < j1; tb += 32) {
            int j = tb + lane;
            float p = 0.f;
            if (j < j1) {
                uint2 en = rec[j];
                float a = __uint_as_float(en.y) + adv;
                a = (a > 0.f) ? a : NSLOPE * a;
                p = __expf(a);                    // safe: |logit| < ~4
                rec[j].y = __float_as_uint(p);    // stash p for broadcast phase
            }
            l += p;
            int cnte = min(32, j1 - tb);
            #pragma unroll 4
            for (int k = 0; k < cnte; ++k) {
                uint2 en = rec[tb + k];           // wave-uniform addr -> LDS broadcast
                acc += __uint_as_float(en.y) *
                       unbf(xlb[(size_t)(en.x & 0xFFFFFu) * COUT + lane]);
            }
        }
        #pragma unroll
        for (int off = 16; off > 0; off >>= 1) l += __shfl_xor(l, off, 32);
        l += ps;
        float h = fmaxf(acc / l + bias_conv[lane], 0.f);
        float pb = h * Wb[lane];
        float pw = h * Ww[lane];
        #pragma unroll
        for (int off = 16; off > 0; off >>= 1) {
            pb += __shfl_xor(pb, off, 32);
            pw += __shfl_xor(pw, off, 32);
        }
        if (lane == 0) {
            out_b[d] = (pb + bb[0]) * mask[d];
            hw[d] = pw;
        }
    }
}

// ---------------- per-edge weights head (4 edges/thread, vectorized) ----------
__global__ void k_weights(const int* __restrict__ ei, const float* __restrict__ hw,
                          const float* __restrict__ bw, float* __restrict__ out_w)
{
    int e4 = blockIdx.x * 256 + threadIdx.x;
    if (e4 < NE / 4) {
        int4 s4 = ((const int4*)ei)[e4];
        int4 d4 = ((const int4*)(ei + NE))[e4];
        float bwv = bw[0];
        float4 o;
        o.x = 0.5f * (hw[s4.x] + hw[d4.x]) + bwv;
        o.y = 0.5f * (hw[s4.y] + hw[d4.y]) + bwv;
        o.z = 0.5f * (hw[s4.z] + hw[d4.z]) + bwv;
        o.w = 0.5f * (hw[s4.w] + hw[d4.w]) + bwv;
        ((float4*)out_w)[e4] = o;
    }
}

extern "C" void kernel_launch(void* const* d_in, const int* in_sizes, int n_in,
                              void* d_out, int out_size, void* d_ws, size_t ws_size,
                              hipStream_t stream)
{
    const float* x        = (const float*)d_in[0];
    const int*   ei       = (const int*)d_in[1];
    const float* ew       = (const float*)d_in[2];
    const float* mask     = (const float*)d_in[3];
    const float* W_src    = (const float*)d_in[4];
    const float* att_src  = (const float*)d_in[5];
    const float* att_dst  = (const float*)d_in[6];
    const float* att_edge = (const float*)d_in[7];
    const float* W_edge   = (const float*)d_in[8];
    const float* bias_c   = (const float*)d_in[9];
    const float* Wb       = (const float*)d_in[10];
    const float* bb       = (const float*)d_in[11];
    const float* Ww       = (const float*)d_in[12];
    const float* bw       = (const float*)d_in[13];
    (void)in_sizes; (void)n_in; (void)out_size; (void)ws_size;

    char* wsp = (char*)d_ws;
    size_t off = 0;
    auto alloc = [&](size_t bytes) -> void* {
        void* p = wsp + off;
        off = (off + bytes + 255) & ~(size_t)255;
        return p;
    };
    unsigned short* xlb    = (unsigned short*)alloc((size_t)NN * COUT * 2);
    float*    a_src  = (float*)alloc((size_t)NN * 4);
    float*    a_dst  = (float*)alloc((size_t)NN * 4);
    float*    stats  = (float*)alloc(256);
    float*    partial= (float*)alloc((size_t)NHB * 4);
    unsigned* part   = (unsigned*)alloc((size_t)NHB * NB * 4);
    unsigned* colsum = (unsigned*)alloc((size_t)NB * 4);
    unsigned* bbase  = (unsigned*)alloc((size_t)(NB + 1) * 4);
    unsigned* done   = (unsigned*)alloc(256);
    uint2*    csr    = (uint2*)alloc((size_t)NE * 8);
    float*    hw     = (float*)alloc((size_t)NN * 4);

    float* out_w = (float*)d_out;
    float* out_b = out_w + NE;

    k_fused1  <<<NGB + NHB, 256, 0, stream>>>(x, W_src, att_src, att_dst,
                                              xlb, a_src, a_dst,
                                              ei + NE, ew, partial, part, done);
    k_scan    <<<NSB, 256, 0, stream>>>(part, colsum, done, partial, W_edge,
                                        att_edge, stats, bbase);
    k_scatter <<<NHB, 256, 0, stream>>>(ei, ew, a_src, stats, part, bbase, csr);
    k_aggr    <<<NB, 256, 0, stream>>>(csr, bbase, a_src, a_dst, xlb, stats,
                                       bias_c, Wb, bb, Ww, mask, out_b, hw);
    k_weights <<<NE / 4 / 256, 256, 0, stream>>>(ei, hw, bw, out_w);
}

// Round 7
// 546.174 us; speedup vs baseline: 1.0499x; 1.0499x over previous
//
#include <hip/hip_runtime.h>
#include <stdint.h>

#define NN 100000
#define NE 3200000
#define FIN 503
#define COUT 32
#define NSLOPE 0.2f

#define BSH 6                    // 64 dst nodes per bucket
#define NB 1563                  // ceil(NN / 64)
#define NGB 1563                 // gemm blocks: ceil(NN/64)
#define NHB 400                  // hist segments / scatter blocks (NGB+NHB <= 2048)
#define EPB (NE / NHB)           // 8000 edges per segment (exact)
#define NSB 7                    // scan blocks: ceil(NB/256)
#define MAXBE 2560               // max edges per bucket (lambda=2048, +11 sigma)

typedef __bf16 bf16x8 __attribute__((ext_vector_type(8)));
typedef float  f32x4  __attribute__((ext_vector_type(4)));

__device__ __forceinline__ unsigned short bf1(float f) {
    unsigned u = __float_as_uint(f);
    u = (u + 0x7FFFu + ((u >> 16) & 1u)) >> 16;   // RNE to bf16
    return (unsigned short)u;
}
__device__ __forceinline__ float unbf(unsigned short h) {
    return __uint_as_float(((unsigned)h) << 16);
}

// ---------------- k_fused1: gemm blocks [0,NGB) + hist blocks [NGB,NGB+NHB) ---
// Heterogeneous dispatch, all 1963 blocks co-resident (15.4 KB LDS, 256 thr ->
// 8 blocks/CU). gemm stages BOTH x and the W K-chunk into LDS as bf16 (RNE at
// stage == old wfrag numerics); A/B fragments are single aligned ds_read_b128.
#define GR 64

__global__ __launch_bounds__(256)
void k_fused1(const float* __restrict__ x, const float* __restrict__ W,
              const float* __restrict__ att_s, const float* __restrict__ att_d,
              unsigned short* __restrict__ xlb,
              float* __restrict__ a_src, float* __restrict__ a_dst,
              const int* __restrict__ ei_dst, const float* __restrict__ ew,
              float* __restrict__ partial, unsigned* __restrict__ part,
              unsigned* __restrict__ done)
{
    __shared__ __align__(16) unsigned short xs[2][GR][40];   // 10.24 KB ping-pong
    __shared__ __align__(16) unsigned short ws[2][32][40];   // 5.12 KB W chunk
    const int t = threadIdx.x;

    if (blockIdx.x >= NGB) {
        // ---------------- hist path ----------------
        unsigned* h = (unsigned*)&xs[0][0][0];               // NB counters (6.3 KB)
        __shared__ float wsum[4];
        const int hb = blockIdx.x - NGB;
        for (int i = t; i < NB; i += 256) h[i] = 0u;
        __syncthreads();
        const int base = hb * EPB;
        for (int i = t; i < EPB; i += 256)
            atomicAdd(&h[ei_dst[base + i] >> BSH], 1u);
        // ew partial sum (float4 grid-stride)
        const float4* ew4 = (const float4*)ew;
        float s = 0.f;
        for (int i = hb * 256 + t; i < NE / 4; i += NHB * 256) {
            float4 v = ew4[i];
            s += v.x + v.y + v.z + v.w;
        }
        #pragma unroll
        for (int off = 32; off > 0; off >>= 1) s += __shfl_xor(s, off);
        if ((t & 63) == 0) wsum[t >> 6] = s;
        __syncthreads();
        if (t == 0) partial[hb] = wsum[0] + wsum[1] + wsum[2] + wsum[3];
        for (int i = t; i < NB; i += 256)
            part[(size_t)hb * NB + i] = h[i];
        return;
    }

    // ---------------- gemm path ----------------
    if (blockIdx.x == 0 && t == 0) *done = 0u;               // for k_scan ticket
    unsigned short* os = &xs[0][0][0];                       // epilogue union (5 KB)
    const int wv = t >> 6, lane = t & 63;
    const int m16 = lane & 15, quad = lane >> 4;
    const int row0 = blockIdx.x * GR;
    const int srow = t >> 5;            // x staging: 8 rows per pass
    const int scol = t & 31;            // x staging: dword within chunk
    const int rowf = wv * 16 + m16;     // fragment row within block
    const int wrow = t >> 3;            // W staging: 0..31
    const int wc   = (t & 7) * 4;       // W staging: 4 consecutive k

    auto stageX = [&](int ch, int buf) {
        const int k = ch * 32 + scol;
        const bool ok = (k < FIN);
        #pragma unroll
        for (int p = 0; p < 8; ++p) {
            int r = p * 8 + srow;
            int rg = row0 + r;
            rg = (rg < NN) ? rg : (NN - 1);
            xs[buf][r][scol] = bf1(ok ? x[(size_t)rg * FIN + k] : 0.f);
        }
    };
    auto stageW = [&](int ch, int buf) {
        const int kb = ch * 32 + wc;
        #pragma unroll
        for (int j = 0; j < 4; ++j) {
            int k = kb + j;
            ws[buf][wrow][wc + j] = bf1((k < FIN) ? W[(size_t)wrow * FIN + k] : 0.f);
        }
    };

    f32x4 acc0 = {0.f, 0.f, 0.f, 0.f};
    f32x4 acc1 = {0.f, 0.f, 0.f, 0.f};

    stageX(0, 0);
    stageW(0, 0);
    for (int ch = 0; ch < 16; ++ch) {
        __syncthreads();                          // stage(ch) ready; buf (ch+1)&1 free
        if (ch < 15) {                            // prefetch next chunk
            stageX(ch + 1, (ch + 1) & 1);
            stageW(ch + 1, (ch + 1) & 1);
        }
        bf16x8 af  = *(const bf16x8*)&xs[ch & 1][rowf][quad * 8];
        bf16x8 b0f = *(const bf16x8*)&ws[ch & 1][m16][quad * 8];
        bf16x8 b1f = *(const bf16x8*)&ws[ch & 1][m16 + 16][quad * 8];
        acc0 = __builtin_amdgcn_mfma_f32_16x16x32_bf16(af, b0f, acc0, 0, 0, 0);
        acc1 = __builtin_amdgcn_mfma_f32_16x16x32_bf16(af, b1f, acc1, 0, 0, 0);
    }
    // last chunk read buf1; os overlays xs[0]; all waves passed the ch=15 barrier

    // epilogue: C-layout (row=quad*4+r, col=m16) -> row-major bf16 via LDS
    #pragma unroll
    for (int r = 0; r < 4; ++r) {
        int rr = wv * 16 + quad * 4 + r;
        os[rr * 40 + m16]      = bf1(acc0[r]);
        os[rr * 40 + 16 + m16] = bf1(acc1[r]);
    }
    __syncthreads();
    {
        int r = t >> 2, c0 = (t & 3) * 8;
        int grow = row0 + r;
        uint4 o = *(const uint4*)&os[r * 40 + c0];
        // attention logits (k_attn folded): partial dot over 8 channels,
        // reduce across the 4 threads of this row (width-4 shuffle)
        float s = 0.f, dd = 0.f;
        const unsigned short* oh = (const unsigned short*)&o;
        #pragma unroll
        for (int j = 0; j < 8; ++j) {
            float v = unbf(oh[j]);
            s  += v * att_s[c0 + j];
            dd += v * att_d[c0 + j];
        }
        s  += __shfl_xor(s, 1, 4);  s  += __shfl_xor(s, 2, 4);
        dd += __shfl_xor(dd, 1, 4); dd += __shfl_xor(dd, 2, 4);
        if (grow < NN) {
            *(uint4*)&xlb[(size_t)grow * COUT + c0] = o;
            if ((t & 3) == 0) { a_src[grow] = s; a_dst[grow] = dd; }
        }
    }
}

// ---------------- k_scan: one bucket per THREAD, coalesced row-major walk -----
__global__ __launch_bounds__(256)
void k_scan(unsigned* __restrict__ part, unsigned* __restrict__ colsum,
            unsigned* __restrict__ done, const float* __restrict__ partial,
            const float* __restrict__ W_edge, const float* __restrict__ att_e,
            float* __restrict__ stats, unsigned* __restrict__ bbase)
{
    const int t = threadIdx.x;
    const int bkt = blockIdx.x * 256 + t;
    if (bkt < NB) {
        unsigned run = 0u;
        #pragma unroll 1
        for (int s = 0; s < NHB; s += 8) {
            unsigned v[8];
            #pragma unroll
            for (int j = 0; j < 8; ++j) v[j] = part[(size_t)(s + j) * NB + bkt];
            #pragma unroll
            for (int j = 0; j < 8; ++j) {
                part[(size_t)(s + j) * NB + bkt] = run;
                run += v[j];
            }
        }
        colsum[bkt] = run;
    }
    __threadfence();
    __syncthreads();
    __shared__ unsigned winner;
    if (t == 0) winner = atomicAdd(done, 1u);
    __syncthreads();
    if (winner != NSB - 1) return;

    // ---- last block: stats finalize ----
    __shared__ float fs[256];
    fs[t] = (t < NHB ? partial[t] : 0.f) + (t + 256 < NHB ? partial[t + 256] : 0.f);
    __syncthreads();
    for (int off = 128; off > 0; off >>= 1) {
        if (t < off) fs[t] += fs[t + off];
        __syncthreads();
    }
    if (t == 0) {
        stats[0] = fs[0];
        float k = 0.f;
        for (int c = 0; c < COUT; ++c) k += W_edge[c] * att_e[c];
        stats[1] = k;
    }
    __syncthreads();
    // ---- bucket-base exclusive scan (atomic loads: device-scope coherent) ----
    __shared__ unsigned sm[256];
    __shared__ unsigned carry;
    if (t == 0) carry = 0u;
    __syncthreads();
    for (int c0 = 0; c0 < NB; c0 += 256) {
        int i = c0 + t;
        unsigned cv = (i < NB) ? atomicAdd(&colsum[i], 0u) : 0u;
        sm[t] = cv;
        for (int off = 1; off < 256; off <<= 1) {
            __syncthreads();
            unsigned tv = (t >= off) ? sm[t - off] : 0u;
            __syncthreads();
            sm[t] += tv;
        }
        __syncthreads();
        if (i < NB) bbase[i] = carry + sm[t] - cv;
        __syncthreads();
        if (t == 0) carry += sm[255];
        __syncthreads();
    }
    if (t == 0) bbase[NB] = carry;                // == NE
}

// ---------------- scatter edges into bucket-grouped order (LDS cursors) -------
__global__ __launch_bounds__(256)
void k_scatter(const int* __restrict__ ei, const float* __restrict__ ew,
               const float* __restrict__ a_src, const float* __restrict__ stats,
               const unsigned* __restrict__ part, const unsigned* __restrict__ bbase,
               uint2* __restrict__ csr)
{
    __shared__ unsigned cur[NB];
    const int b = blockIdx.x;
    const int t = threadIdx.x;
    for (int i = t; i < NB; i += 256)
        cur[i] = bbase[i] + part[(size_t)b * NB + i];
    __syncthreads();
    const float kc = stats[1];
    const int base = b * EPB;
    for (int i = t; i < EPB; i += 256) {
        int e = base + i;
        int s = ei[e];
        int d = ei[NE + e];
        float pre = a_src[s] + kc * ew[e];
        unsigned pos = atomicAdd(&cur[d >> BSH], 1u);
        csr[pos] = make_uint2((unsigned)s | ((unsigned)(d & 63) << 20),
                              __float_as_uint(pre));
    }
}

// ---------------- per-bucket softmax aggregation --------------------------------
// Two-pass in-place LDS counting sort (pass 2 is L1-hot). 21 KB LDS, 44 VGPR ->
// 7 blocks/CU -> whole 1563-block grid resident in one scheduling round.
__global__ __launch_bounds__(256)
void k_aggr(const uint2* __restrict__ csr, const unsigned* __restrict__ bbase,
            const float* __restrict__ a_src, const float* __restrict__ a_dst,
            const unsigned short* __restrict__ xlb, const float* __restrict__ stats,
            const float* __restrict__ bias_conv, const float* __restrict__ Wb,
            const float* __restrict__ bb, const float* __restrict__ Ww,
            const float* __restrict__ mask, float* __restrict__ out_b,
            float* __restrict__ hw)
{
    __shared__ uint2 rec[MAXBE];
    __shared__ unsigned seg[65], cur[64];
    const int t = threadIdx.x;
    const int b = blockIdx.x;
    const int jb = (int)bbase[b];
    int ne = (int)bbase[b + 1] - jb;
    if (ne > MAXBE) ne = MAXBE;                   // statistically unreachable

    if (t < 64) cur[t] = 0u;
    __syncthreads();
    // pass 1: histogram of dst-locals
    for (int i = t; i < ne; i += 256)
        atomicAdd(&cur[csr[jb + i].x >> 20], 1u);
    __syncthreads();
    // exclusive scan of 64 counters in wave 0 (shfl-based)
    if (t < 64) {
        unsigned v = cur[t];
        unsigned s = v;
        #pragma unroll
        for (int off = 1; off < 64; off <<= 1) {
            unsigned u = __shfl_up(s, off, 64);
            if (t >= off) s += u;
        }
        seg[t + 1] = s;           // inclusive
        cur[t] = s - v;           // exclusive -> running cursor
        if (t == 0) seg[0] = 0u;
    }
    __syncthreads();
    // pass 2: scatter into sorted position (csr segment L1-hot from pass 1)
    for (int i = t; i < ne; i += 256) {
        uint2 r = csr[jb + i];
        unsigned pos = atomicAdd(&cur[r.x >> 20], 1u);
        rec[pos] = r;
    }
    __syncthreads();

    const float kmean = stats[1] * (stats[0] * (1.f / NE));   // kc * mean(ew)
    const int lane = t & 31;
    for (int dl = t >> 5; dl < 64; dl += 8) {
        int d = (b << BSH) + dl;
        if (d >= NN) continue;                    // warp-uniform
        const float adv = a_dst[d];
        // self loop (edge_attr = mean), computed inline
        float a0 = a_src[d] + adv + kmean;
        a0 = (a0 > 0.f) ? a0 : NSLOPE * a0;
        const float ps = __expf(a0);
        float l = 0.f;
        float acc = ps * unbf(xlb[(size_t)d * COUT + lane]);
        const int j0 = (int)seg[dl], j1 = (int)seg[dl + 1];
        for (int tb = j0; tb < j1; tb += 32) {
            int j = tb + lane;
            float p = 0.f;
            if (j < j1) {
                uint2 en = rec[j];
                float a = __uint_as_float(en.y) + adv;
                a = (a > 0.f) ? a : NSLOPE * a;
                p = __expf(a);                    // safe: |logit| < ~4
                rec[j].y = __float_as_uint(p);    // stash p for broadcast phase
            }
            l += p;
            int cnte = min(32, j1 - tb);
            #pragma unroll 4
            for (int k = 0; k < cnte; ++k) {
                uint2 en = rec[tb + k];           // wave-uniform addr -> LDS broadcast
                acc += __uint_as_float(en.y) *
                       unbf(xlb[(size_t)(en.x & 0xFFFFFu) * COUT + lane]);
            }
        }
        #pragma unroll
        for (int off = 16; off > 0; off >>= 1) l += __shfl_xor(l, off, 32);
        l += ps;
        float h = fmaxf(acc / l + bias_conv[lane], 0.f);
        float pb = h * Wb[lane];
        float pw = h * Ww[lane];
        #pragma unroll
        for (int off = 16; off > 0; off >>= 1) {
            pb += __shfl_xor(pb, off, 32);
            pw += __shfl_xor(pw, off, 32);
        }
        if (lane == 0) {
            out_b[d] = (pb + bb[0]) * mask[d];
            hw[d] = pw;
        }
    }
}

// ---------------- per-edge weights head (4 edges/thread, vectorized) ----------
__global__ void k_weights(const int* __restrict__ ei, const float* __restrict__ hw,
                          const float* __restrict__ bw, float* __restrict__ out_w)
{
    int e4 = blockIdx.x * 256 + threadIdx.x;
    if (e4 < NE / 4) {
        int4 s4 = ((const int4*)ei)[e4];
        int4 d4 = ((const int4*)(ei + NE))[e4];
        float bwv = bw[0];
        float4 o;
        o.x = 0.5f * (hw[s4.x] + hw[d4.x]) + bwv;
        o.y = 0.5f * (hw[s4.y] + hw[d4.y]) + bwv;
        o.z = 0.5f * (hw[s4.z] + hw[d4.z]) + bwv;
        o.w = 0.5f * (hw[s4.w] + hw[d4.w]) + bwv;
        ((float4*)out_w)[e4] = o;
    }
}

extern "C" void kernel_launch(void* const* d_in, const int* in_sizes, int n_in,
                              void* d_out, int out_size, void* d_ws, size_t ws_size,
                              hipStream_t stream)
{
    const float* x        = (const float*)d_in[0];
    const int*   ei       = (const int*)d_in[1];
    const float* ew       = (const float*)d_in[2];
    const float* mask     = (const float*)d_in[3];
    const float* W_src    = (const float*)d_in[4];
    const float* att_src  = (const float*)d_in[5];
    const float* att_dst  = (const float*)d_in[6];
    const float* att_edge = (const float*)d_in[7];
    const float* W_edge   = (const float*)d_in[8];
    const float* bias_c   = (const float*)d_in[9];
    const float* Wb       = (const float*)d_in[10];
    const float* bb       = (const float*)d_in[11];
    const float* Ww       = (const float*)d_in[12];
    const float* bw       = (const float*)d_in[13];
    (void)in_sizes; (void)n_in; (void)out_size; (void)ws_size;

    char* wsp = (char*)d_ws;
    size_t off = 0;
    auto alloc = [&](size_t bytes) -> void* {
        void* p = wsp + off;
        off = (off + bytes + 255) & ~(size_t)255;
        return p;
    };
    unsigned short* xlb    = (unsigned short*)alloc((size_t)NN * COUT * 2);
    float*    a_src  = (float*)alloc((size_t)NN * 4);
    float*    a_dst  = (float*)alloc((size_t)NN * 4);
    float*    stats  = (float*)alloc(256);
    float*    partial= (float*)alloc((size_t)NHB * 4);
    unsigned* part   = (unsigned*)alloc((size_t)NHB * NB * 4);
    unsigned* colsum = (unsigned*)alloc((size_t)NB * 4);
    unsigned* bbase  = (unsigned*)alloc((size_t)(NB + 1) * 4);
    unsigned* done   = (unsigned*)alloc(256);
    uint2*    csr    = (uint2*)alloc((size_t)NE * 8);
    float*    hw     = (float*)alloc((size_t)NN * 4);

    float* out_w = (float*)d_out;
    float* out_b = out_w + NE;

    k_fused1  <<<NGB + NHB, 256, 0, stream>>>(x, W_src, att_src, att_dst,
                                              xlb, a_src, a_dst,
                                              ei + NE, ew, partial, part, done);
    k_scan    <<<NSB, 256, 0, stream>>>(part, colsum, done, partial, W_edge,
                                        att_edge, stats, bbase);
    k_scatter <<<NHB, 256, 0, stream>>>(ei, ew, a_src, stats, part, bbase, csr);
    k_aggr    <<<NB, 256, 0, stream>>>(csr, bbase, a_src, a_dst, xlb, stats,
                                       bias_c, Wb, bb, Ww, mask, out_b, hw);
    k_weights <<<NE / 4 / 256, 256, 0, stream>>>(ei, hw, bw, out_w);
}